// Round 5
// baseline (1457.905 us; speedup 1.0000x reference)
//
#include <hip/hip_runtime.h>
#include <hip/hip_bf16.h>

typedef __attribute__((ext_vector_type(8))) short bf16x8;
typedef __attribute__((ext_vector_type(4))) float f32x4;

#define MFMA16(a,b,c) __builtin_amdgcn_mfma_f32_16x16x32_bf16(a,b,c,0,0,0)

__device__ inline ushort f2bf(float f){
  union { float f; uint u; } v; v.f = f;
  uint r = v.u + 0x7FFFu + ((v.u >> 16) & 1u);
  return (ushort)(r >> 16);
}
__device__ inline float sigf(float x){ return 1.f/(1.f+__expf(-x)); }
__device__ inline float tanhf_(float x){ return 2.f/(1.f+__expf(-2.f*x)) - 1.f; }

__device__ inline void gload_lds16(const ushort* g, ushort* lds){
  __builtin_amdgcn_global_load_lds(
      (const __attribute__((address_space(1))) void*)g,
      (__attribute__((address_space(3))) void*)lds, 16, 0, 0);
}

// ---------------- weight fp32 -> bf16 conversion ----------------
__global__ void convert_weights(const float* __restrict__ s0, const float* __restrict__ s1,
                                const float* __restrict__ s2, const float* __restrict__ s3,
                                ushort* __restrict__ dst){
  size_t i4 = ((size_t)blockIdx.x*256 + threadIdx.x)*4;
  int tsel = (int)(i4 >> 21);
  const float* s = (tsel & 2) ? ((tsel & 1) ? s3 : s2) : ((tsel & 1) ? s1 : s0);
  size_t off = i4 & 2097151u;
  float4 v = *(const float4*)&s[off];
  ushort4 o; o.x=f2bf(v.x); o.y=f2bf(v.y); o.z=f2bf(v.z); o.w=f2bf(v.w);
  *(ushort4*)&dst[i4] = o;
}

// ---------------- embed ----------------
__global__ void embed_kernel(const float* __restrict__ obsVel, const float* __restrict__ mean,
                             const float* __restrict__ stdv, const float* __restrict__ encW,
                             const float* __restrict__ encb, ushort* __restrict__ embed){
  int idx = blockIdx.x*256 + threadIdx.x;   // < 32768*64
  int row = idx >> 6, c8 = (idx & 63) * 8;
  float x0 = (obsVel[row*2+0] - mean[0]) / stdv[0];
  float x1 = (obsVel[row*2+1] - mean[1]) / stdv[1];
  ushort o[8];
  #pragma unroll
  for (int j=0;j<8;j++){
    int col = c8 + j;
    o[j] = f2bf(x0*encW[col] + x1*encW[512+col] + encb[col]);
  }
  *(uint4*)&embed[(size_t)row*512 + c8] = *(const uint4*)o;
}

// ---------------- fused LSTM cell step ----------------
// 128 threads (2 waves). Block g-tile 128 rows x 128 gcols (4 gates x 32).
// Wave tile 64x128: af[4] x bf[8] -> 32 MFMA per 12 ds_read_b128
// (341 B LDS/MFMA, was 512). 2 LDS bufs x 16 KB = 32 KB -> 4 blocks/CU,
// 8 waves/CU. XOR row-pair swizzle (conflict-free, round-4 proven).
// C/bias loaded AFTER K-loop (VGPR budget: acc 128 + frags 48 + addr ~30).
#define NKT_SEG 16   // K=512 per segment / BK=32

__global__ __launch_bounds__(128, 2) void lstm_cell_kernel(
    const ushort* __restrict__ A0, int lda0,
    const ushort* __restrict__ A1, int lda1,
    const ushort* __restrict__ B0,
    const ushort* __restrict__ B1,
    const float*  __restrict__ bias,
    float* __restrict__ C,
    ushort* __restrict__ H0, int ldh0,
    ushort* __restrict__ H1, int ldh1,
    int nSeg, int czero)
{
  __shared__ ushort aL[2][4096];   // 64 LDS-rows x 64 ushort (128 B); tile 128r x 32k
  __shared__ ushort bL[2][4096];
  const int tid = threadIdx.x;
  const int w = tid >> 6, lane = tid & 63;   // w in {0,1}
  const int bm = blockIdx.y * 128;
  const int bn = blockIdx.x * 32;            // gate-local col base

  f32x4 acc[4][8];
  #pragma unroll
  for (int m=0;m<4;m++)
    #pragma unroll
    for (int n=0;n<8;n++) acc[m][n] = (f32x4)0.f;

  // ---- staging addresses: 4 chunks/thread/tile (A) + 4 (B); inverse swizzle ----
  // chunk i -> LDS byte i*16; (rl=i>>3, s=i&7) -> x=s^(rl&7): r=(x>>2)*64+rl, ch=x&3
  int arow[4], brow[4], chS[4], ldsO[4];
  #pragma unroll
  for (int p=0;p<4;p++){
    int i = p*128 + tid;
    int rl = i>>3, s = i&7, x = s ^ (rl&7);
    int r = ((x>>2)<<6) + rl;
    arow[p] = bm + r;
    brow[p] = ((r>>5)<<9) + bn + (r&31);
    chS[p]  = x & 3;
    ldsO[p] = (p*128 + (tid & ~63)) * 8;   // ushort idx of wave-uniform base
  }

  // ---- frag read offsets (loop-invariant) ----
  const int chR = lane >> 4;
  int aOff[4], bOff[8];
  #pragma unroll
  for (int m=0;m<4;m++){
    int row = w*64 + m*16 + (lane&15);
    int slot = (((row>>6)<<2) + chR) ^ (row&7);
    aOff[m] = (row&63)*64 + slot*8;
  }
  #pragma unroll
  for (int n=0;n<8;n++){
    int row = (n>>1)*32 + (n&1)*16 + (lane&15);
    int slot = (((row>>6)<<2) + chR) ^ (row&7);
    bOff[n] = (row&63)*64 + slot*8;
  }

  #define STAGE(bi, kt) do { \
    const ushort* Aseg = ((kt) < NKT_SEG) ? A0 : A1; \
    const int lda_     = ((kt) < NKT_SEG) ? lda0 : lda1; \
    const ushort* Bseg = ((kt) < NKT_SEG) ? B0 : B1; \
    const int k0_ = ((kt) & (NKT_SEG-1)) << 5; \
    _Pragma("unroll") \
    for (int p=0;p<4;p++){ \
      gload_lds16(Aseg + (size_t)arow[p]*lda_ + k0_ + chS[p]*8, &aL[bi][ldsO[p]]); \
      gload_lds16(Bseg + ((size_t)brow[p]<<9) + k0_ + chS[p]*8, &bL[bi][ldsO[p]]); \
    } \
  } while(0)

  const int nkt = nSeg * NKT_SEG;

  STAGE(0, 0);
  __syncthreads();

  for (int kt=0; kt<nkt; ++kt){
    const int cur = kt & 1;
    if (kt+1 < nkt) STAGE(cur^1, kt+1);
    bf16x8 af[4], bf[8];
    #pragma unroll
    for (int m=0;m<4;m++) af[m] = *(const bf16x8*)&aL[cur][aOff[m]];
    #pragma unroll
    for (int n=0;n<8;n++) bf[n] = *(const bf16x8*)&bL[cur][bOff[n]];
    __builtin_amdgcn_s_setprio(1);
    #pragma unroll
    for (int m=0;m<4;m++)
      #pragma unroll
      for (int n=0;n<8;n++)
        acc[m][n] = MFMA16(af[m], bf[n], acc[m][n]);
    __builtin_amdgcn_s_setprio(0);
    __syncthreads();
  }
  #undef STAGE

  // ---- epilogue: bias + gates, c update, h writes (loads placed here to cap VGPR) ----
  const int r0 = bm + w*64 + ((lane>>4)<<2);
  #pragma unroll
  for (int cc=0;cc<2;cc++){
    const int ccol = bn + cc*16 + (lane&15);
    const float bi = bias[ccol];
    const float bff = bias[512+ccol];
    const float bg = bias[1024+ccol];
    const float bo = bias[1536+ccol];
    #pragma unroll
    for (int m=0;m<4;m++){
      #pragma unroll
      for (int reg=0;reg<4;reg++){
        const int row = r0 + m*16 + reg;
        float gi = acc[m][0+cc][reg] + bi;
        float gf = acc[m][2+cc][reg] + bff;
        float gg = acc[m][4+cc][reg] + bg;
        float go = acc[m][6+cc][reg] + bo;
        size_t cidx = (size_t)row*512 + ccol;
        float cv = czero ? 0.f : C[cidx];
        float cn = sigf(gf)*cv + sigf(gi)*tanhf_(gg);
        float hv = sigf(go)*tanhf_(cn);
        C[cidx] = cn;
        ushort hb = f2bf(hv);
        H0[(size_t)row*ldh0 + ccol] = hb;
        if (H1) H1[(size_t)row*ldh1 + ccol] = hb;
      }
    }
  }
}

// ---------------- projection + cumsum ----------------
__global__ void final_kernel(const ushort* __restrict__ pred, const float* __restrict__ decW,
                             const float* __restrict__ decb, const float* __restrict__ mean,
                             const float* __restrict__ stdv, const float* __restrict__ obs,
                             float* __restrict__ out){
  int w = threadIdx.x >> 6, lane = threadIdx.x & 63;
  int b = blockIdx.x*4 + w;
  float w0[8], w1[8];
  #pragma unroll
  for (int j=0;j<8;j++){
    int k = lane*8 + j;
    w0[j] = decW[k*2+0];
    w1[j] = decW[k*2+1];
  }
  float cum0 = 0.f, cum1 = 0.f;
  float m0 = mean[0], m1 = mean[1], sv0 = stdv[0], sv1 = stdv[1];
  float o0 = obs[(b*8+7)*2+0], o1 = obs[(b*8+7)*2+1];
  float db0 = decb[0], db1 = decb[1];
  for (int t=0;t<12;t++){
    const uint4 q = *(const uint4*)&pred[((size_t)b*12+t)*512 + lane*8];
    uint u[4] = {q.x,q.y,q.z,q.w};
    float s0=0.f, s1=0.f;
    #pragma unroll
    for (int p=0;p<4;p++){
      float lo = __uint_as_float(u[p]<<16);
      float hi = __uint_as_float(u[p]&0xffff0000u);
      s0 += lo*w0[2*p] + hi*w0[2*p+1];
      s1 += lo*w1[2*p] + hi*w1[2*p+1];
    }
    #pragma unroll
    for (int off=32; off>0; off>>=1){ s0 += __shfl_down(s0, off); s1 += __shfl_down(s1, off); }
    if (lane==0){
      cum0 += (s0+db0)*sv0 + m0;
      cum1 += (s1+db1)*sv1 + m1;
      out[((size_t)b*12+t)*2+0] = cum0 + o0;
      out[((size_t)b*12+t)*2+1] = cum1 + o1;
    }
  }
}

extern "C" void kernel_launch(void* const* d_in, const int* in_sizes, int n_in,
                              void* d_out, int out_size, void* d_ws, size_t ws_size,
                              hipStream_t stream) {
  const float* obs      = (const float*)d_in[0];
  const float* obsVel   = (const float*)d_in[1];
  const float* mean     = (const float*)d_in[2];
  const float* stdv     = (const float*)d_in[3];
  const float* encW     = (const float*)d_in[5];
  const float* encb     = (const float*)d_in[6];
  const float* decW     = (const float*)d_in[7];
  const float* decb     = (const float*)d_in[8];
  const float* lstm_Wih = (const float*)d_in[9];
  const float* lstm_Whh = (const float*)d_in[10];
  const float* lstm_b   = (const float*)d_in[11];
  const float* cell_Wih = (const float*)d_in[12];
  const float* cell_Whh = (const float*)d_in[13];
  const float* cell_b   = (const float*)d_in[14];

  char* ws = (char*)d_ws;
  ushort* wbf   = (ushort*)ws;                       // 16 MB
  ushort* embed = (ushort*)(ws + (16ull<<20));       // 32 MB
  ushort* h0[2] = {(ushort*)(ws + (48ull<<20)), (ushort*)(ws + (52ull<<20))};
  ushort* h1[2] = {(ushort*)(ws + (56ull<<20)), (ushort*)(ws + (60ull<<20))};
  float*  c0    = (float*)(ws + (64ull<<20));
  float*  c1    = (float*)(ws + (72ull<<20));
  ushort* pred  = (ushort*)(ws + (80ull<<20));       // 48 MB

  ushort* w_lstm_ih = wbf;
  ushort* w_lstm_hh = wbf + 2097152;
  ushort* w_cell_ih = wbf + 4194304;
  ushort* w_cell_hh = wbf + 6291456;

  convert_weights<<<8192, 256, 0, stream>>>(lstm_Wih, lstm_Whh, cell_Wih, cell_Whh, wbf);
  embed_kernel<<<8192, 256, 0, stream>>>(obsVel, mean, stdv, encW, encb, embed);

  dim3 grid(16, 32);
  int cur0 = 0, cur1 = 0;
  for (int t=0;t<8;t++){
    int ns = (t==0) ? 1 : 2;
    int cz = (t==0) ? 1 : 0;
    lstm_cell_kernel<<<grid, 128, 0, stream>>>(embed + t*512, 4096, h0[cur0], 512,
        w_lstm_ih, w_lstm_hh, lstm_b, c0, h0[cur0^1], 512, (ushort*)nullptr, 0, ns, cz);
    lstm_cell_kernel<<<grid, 128, 0, stream>>>(h0[cur0^1], 512, h1[cur1], 512,
        w_lstm_ih + 1048576, w_lstm_hh + 1048576, lstm_b + 2048, c1, h1[cur1^1], 512,
        (t==7) ? pred : (ushort*)nullptr, 6144, ns, cz);
    cur0 ^= 1; cur1 ^= 1;
  }
  for (int s=1;s<12;s++){
    lstm_cell_kernel<<<grid, 128, 0, stream>>>(pred + (s-1)*512, 6144, h0[cur0], 512,
        w_cell_ih, w_cell_hh, cell_b, c0, h0[cur0^1], 512, (ushort*)nullptr, 0, 2, 0);
    lstm_cell_kernel<<<grid, 128, 0, stream>>>(h0[cur0^1], 512, h1[cur1], 512,
        w_cell_ih + 1048576, w_cell_hh + 1048576, cell_b + 2048, c1, h1[cur1^1], 512,
        pred + s*512, 6144, 2, 0);
    cur0 ^= 1; cur1 ^= 1;
  }
  final_kernel<<<1024, 256, 0, stream>>>(pred, decW, decb, mean, stdv, obs, (float*)d_out);
}

// Round 6
// 1122.107 us; speedup vs baseline: 1.2993x; 1.2993x over previous
//
#include <hip/hip_runtime.h>
#include <hip/hip_bf16.h>

typedef __attribute__((ext_vector_type(8))) short bf16x8;
typedef __attribute__((ext_vector_type(4))) float f32x4;

#define MFMA16(a,b,c) __builtin_amdgcn_mfma_f32_16x16x32_bf16(a,b,c,0,0,0)

__device__ inline ushort f2bf(float f){
  union { float f; uint u; } v; v.f = f;
  uint r = v.u + 0x7FFFu + ((v.u >> 16) & 1u);
  return (ushort)(r >> 16);
}
__device__ inline float sigf(float x){ return 1.f/(1.f+__expf(-x)); }
__device__ inline float tanhf_(float x){ return 2.f/(1.f+__expf(-2.f*x)) - 1.f; }

__device__ inline void gload_lds16(const ushort* g, ushort* lds){
  __builtin_amdgcn_global_load_lds(
      (const __attribute__((address_space(1))) void*)g,
      (__attribute__((address_space(3))) void*)lds, 16, 0, 0);
}

// ---------------- weight fp32 -> bf16 conversion ----------------
__global__ void convert_weights(const float* __restrict__ s0, const float* __restrict__ s1,
                                const float* __restrict__ s2, const float* __restrict__ s3,
                                ushort* __restrict__ dst){
  size_t i4 = ((size_t)blockIdx.x*256 + threadIdx.x)*4;
  int tsel = (int)(i4 >> 21);
  const float* s = (tsel & 2) ? ((tsel & 1) ? s3 : s2) : ((tsel & 1) ? s1 : s0);
  size_t off = i4 & 2097151u;
  float4 v = *(const float4*)&s[off];
  ushort4 o; o.x=f2bf(v.x); o.y=f2bf(v.y); o.z=f2bf(v.z); o.w=f2bf(v.w);
  *(ushort4*)&dst[i4] = o;
}

// ---------------- embed ----------------
__global__ void embed_kernel(const float* __restrict__ obsVel, const float* __restrict__ mean,
                             const float* __restrict__ stdv, const float* __restrict__ encW,
                             const float* __restrict__ encb, ushort* __restrict__ embed){
  int idx = blockIdx.x*256 + threadIdx.x;   // < 32768*64
  int row = idx >> 6, c8 = (idx & 63) * 8;
  float x0 = (obsVel[row*2+0] - mean[0]) / stdv[0];
  float x1 = (obsVel[row*2+1] - mean[1]) / stdv[1];
  ushort o[8];
  #pragma unroll
  for (int j=0;j<8;j++){
    int col = c8 + j;
    o[j] = f2bf(x0*encW[col] + x1*encW[512+col] + encb[col]);
  }
  *(uint4*)&embed[(size_t)row*512 + c8] = *(const uint4*)o;
}

// ---------------- fused LSTM cell step ----------------
// 256 thr (4 waves stacked in M; wave tile 32 rows x 128 gcols). Block tile
// 128 x 128 of g. BK=64, 16 K-iters. A: DIRECT global->reg frags (rows are
// wave-private -> no reuse -> no LDS), prefetched 1 iter ahead. B: LDS,
// 2 bufs x 16 KB, XOR swizzle slot = ch ^ (row&7) (conflict-free, proven
// rounds 4/5), staged via inverse-swizzled global source, linear LDS dest.
// One __syncthreads per iter (vmcnt(0)+lgkmcnt(0) drain lands ~compute-time
// after issue of both A-loads and B-stage).
#define NKT_SEG 8   // K=512 per segment / BK=64

__global__ __launch_bounds__(256, 2) void lstm_cell_kernel(
    const ushort* __restrict__ A0, int lda0,
    const ushort* __restrict__ A1, int lda1,
    const ushort* __restrict__ B0,
    const ushort* __restrict__ B1,
    const float*  __restrict__ bias,
    float* __restrict__ C,
    ushort* __restrict__ H0, int ldh0,
    ushort* __restrict__ H1, int ldh1,
    int nSeg, int czero)
{
  __shared__ ushort bL[2][8192];   // 128 g-rows x 64 k bf16, swizzled
  const int tid = threadIdx.x;
  const int w = tid >> 6, lane = tid & 63;
  const int bm = blockIdx.y * 128;
  const int bn = blockIdx.x * 32;            // gate-local col base

  f32x4 acc[2][8];
  #pragma unroll
  for (int m=0;m<2;m++)
    #pragma unroll
    for (int n=0;n<8;n++) acc[m][n] = (f32x4)0.f;

  // ---- B staging: 4 chunks/thread/tile; inverse swizzle ----
  // tile chunk i (0..1023) -> LDS byte i*16; r=i>>3, s=i&7, src ch=s^(r&7)
  int boff[4], ldsO[4];
  #pragma unroll
  for (int p=0;p<4;p++){
    int i = p*256 + tid;
    int r = i>>3, s = i&7, ch = s ^ (r&7);
    boff[p] = (((r>>5)<<9) + bn + (r&31))*512 + ch*8;   // elem offset in B seg
    ldsO[p] = (p*256 + (tid & ~63)) * 8;                // wave-uniform base (ushorts)
  }

  // ---- A direct-load geometry (wave-private rows) ----
  const int arow0 = bm + w*32 + (lane&15);
  const int arow1 = arow0 + 16;
  const int ca = (lane>>4)*8;    // k-chunk within 64-elem K-step (kk=1 -> +32)

  // ---- B frag read offsets (ushort units); kk=1 -> ^32 ----
  int bOff[8];
  #pragma unroll
  for (int n=0;n<8;n++){
    int row = (n>>1)*32 + (n&1)*16 + (lane&15);
    int slot = (lane>>4) ^ (row&7);
    bOff[n] = row*64 + slot*8;
  }

  #define STAGE_B(bi, kt) do { \
    const ushort* Bseg = ((kt) < NKT_SEG) ? B0 : B1; \
    const int k0_ = ((kt) & (NKT_SEG-1)) << 6; \
    _Pragma("unroll") \
    for (int p=0;p<4;p++) \
      gload_lds16(Bseg + boff[p] + k0_, &bL[bi][ldsO[p]]); \
  } while(0)

  #define LOAD_A(AF, kt) do { \
    const ushort* Aseg = ((kt) < NKT_SEG) ? A0 : A1; \
    const int lda_     = ((kt) < NKT_SEG) ? lda0 : lda1; \
    const int k0_ = ((kt) & (NKT_SEG-1)) << 6; \
    const ushort* pa0_ = Aseg + (size_t)arow0*lda_ + k0_ + ca; \
    const ushort* pa1_ = Aseg + (size_t)arow1*lda_ + k0_ + ca; \
    AF[0][0] = *(const bf16x8*)pa0_;  AF[0][1] = *(const bf16x8*)(pa0_+32); \
    AF[1][0] = *(const bf16x8*)pa1_;  AF[1][1] = *(const bf16x8*)(pa1_+32); \
  } while(0)

  #define COMPUTE(bi, AF) do { \
    bf16x8 bfr[8]; \
    _Pragma("unroll") \
    for (int n=0;n<8;n++) bfr[n] = *(const bf16x8*)&bL[bi][bOff[n]]; \
    __builtin_amdgcn_s_setprio(1); \
    _Pragma("unroll") \
    for (int m=0;m<2;m++) \
      _Pragma("unroll") \
      for (int n=0;n<8;n++) acc[m][n] = MFMA16(AF[m][0], bfr[n], acc[m][n]); \
    __builtin_amdgcn_s_setprio(0); \
    _Pragma("unroll") \
    for (int n=0;n<8;n++) bfr[n] = *(const bf16x8*)&bL[bi][bOff[n]^32]; \
    __builtin_amdgcn_s_setprio(1); \
    _Pragma("unroll") \
    for (int m=0;m<2;m++) \
      _Pragma("unroll") \
      for (int n=0;n<8;n++) acc[m][n] = MFMA16(AF[m][1], bfr[n], acc[m][n]); \
    __builtin_amdgcn_s_setprio(0); \
  } while(0)

  const int nkt = nSeg * NKT_SEG;   // 8 or 16, always even
  bf16x8 afA[2][2], afB[2][2];

  STAGE_B(0, 0);
  LOAD_A(afA, 0);
  __syncthreads();

  for (int kt = 0; kt < nkt-2; kt += 2){
    STAGE_B(1, kt+1);  LOAD_A(afB, kt+1);
    COMPUTE(0, afA);
    __syncthreads();
    STAGE_B(0, kt+2);  LOAD_A(afA, kt+2);
    COMPUTE(1, afB);
    __syncthreads();
  }
  STAGE_B(1, nkt-1);  LOAD_A(afB, nkt-1);
  COMPUTE(0, afA);
  __syncthreads();
  COMPUTE(1, afB);

  #undef STAGE_B
  #undef LOAD_A
  #undef COMPUTE

  // ---- epilogue: bias + gates, c update, h writes ----
  const int r0 = bm + w*32 + ((lane>>4)<<2);
  #pragma unroll
  for (int cc=0;cc<2;cc++){
    const int ccol = bn + cc*16 + (lane&15);
    const float bi = bias[ccol];
    const float bff = bias[512+ccol];
    const float bg = bias[1024+ccol];
    const float bo = bias[1536+ccol];
    #pragma unroll
    for (int m=0;m<2;m++){
      #pragma unroll
      for (int reg=0;reg<4;reg++){
        const int row = r0 + m*16 + reg;
        float gi = acc[m][0+cc][reg] + bi;
        float gf = acc[m][2+cc][reg] + bff;
        float gg = acc[m][4+cc][reg] + bg;
        float go = acc[m][6+cc][reg] + bo;
        size_t cidx = (size_t)row*512 + ccol;
        float cv = czero ? 0.f : C[cidx];
        float cn = sigf(gf)*cv + sigf(gi)*tanhf_(gg);
        float hv = sigf(go)*tanhf_(cn);
        C[cidx] = cn;
        ushort hb = f2bf(hv);
        H0[(size_t)row*ldh0 + ccol] = hb;
        if (H1) H1[(size_t)row*ldh1 + ccol] = hb;
      }
    }
  }
}

// ---------------- projection + cumsum ----------------
__global__ void final_kernel(const ushort* __restrict__ pred, const float* __restrict__ decW,
                             const float* __restrict__ decb, const float* __restrict__ mean,
                             const float* __restrict__ stdv, const float* __restrict__ obs,
                             float* __restrict__ out){
  int w = threadIdx.x >> 6, lane = threadIdx.x & 63;
  int b = blockIdx.x*4 + w;
  float w0[8], w1[8];
  #pragma unroll
  for (int j=0;j<8;j++){
    int k = lane*8 + j;
    w0[j] = decW[k*2+0];
    w1[j] = decW[k*2+1];
  }
  float cum0 = 0.f, cum1 = 0.f;
  float m0 = mean[0], m1 = mean[1], sv0 = stdv[0], sv1 = stdv[1];
  float o0 = obs[(b*8+7)*2+0], o1 = obs[(b*8+7)*2+1];
  float db0 = decb[0], db1 = decb[1];
  for (int t=0;t<12;t++){
    const uint4 q = *(const uint4*)&pred[((size_t)b*12+t)*512 + lane*8];
    uint u[4] = {q.x,q.y,q.z,q.w};
    float s0=0.f, s1=0.f;
    #pragma unroll
    for (int p=0;p<4;p++){
      float lo = __uint_as_float(u[p]<<16);
      float hi = __uint_as_float(u[p]&0xffff0000u);
      s0 += lo*w0[2*p] + hi*w0[2*p+1];
      s1 += lo*w1[2*p] + hi*w1[2*p+1];
    }
    #pragma unroll
    for (int off=32; off>0; off>>=1){ s0 += __shfl_down(s0, off); s1 += __shfl_down(s1, off); }
    if (lane==0){
      cum0 += (s0+db0)*sv0 + m0;
      cum1 += (s1+db1)*sv1 + m1;
      out[((size_t)b*12+t)*2+0] = cum0 + o0;
      out[((size_t)b*12+t)*2+1] = cum1 + o1;
    }
  }
}

extern "C" void kernel_launch(void* const* d_in, const int* in_sizes, int n_in,
                              void* d_out, int out_size, void* d_ws, size_t ws_size,
                              hipStream_t stream) {
  const float* obs      = (const float*)d_in[0];
  const float* obsVel   = (const float*)d_in[1];
  const float* mean     = (const float*)d_in[2];
  const float* stdv     = (const float*)d_in[3];
  const float* encW     = (const float*)d_in[5];
  const float* encb     = (const float*)d_in[6];
  const float* decW     = (const float*)d_in[7];
  const float* decb     = (const float*)d_in[8];
  const float* lstm_Wih = (const float*)d_in[9];
  const float* lstm_Whh = (const float*)d_in[10];
  const float* lstm_b   = (const float*)d_in[11];
  const float* cell_Wih = (const float*)d_in[12];
  const float* cell_Whh = (const float*)d_in[13];
  const float* cell_b   = (const float*)d_in[14];

  char* ws = (char*)d_ws;
  ushort* wbf   = (ushort*)ws;                       // 16 MB
  ushort* embed = (ushort*)(ws + (16ull<<20));       // 32 MB
  ushort* h0[2] = {(ushort*)(ws + (48ull<<20)), (ushort*)(ws + (52ull<<20))};
  ushort* h1[2] = {(ushort*)(ws + (56ull<<20)), (ushort*)(ws + (60ull<<20))};
  float*  c0    = (float*)(ws + (64ull<<20));
  float*  c1    = (float*)(ws + (72ull<<20));
  ushort* pred  = (ushort*)(ws + (80ull<<20));       // 48 MB

  ushort* w_lstm_ih = wbf;
  ushort* w_lstm_hh = wbf + 2097152;
  ushort* w_cell_ih = wbf + 4194304;
  ushort* w_cell_hh = wbf + 6291456;

  convert_weights<<<8192, 256, 0, stream>>>(lstm_Wih, lstm_Whh, cell_Wih, cell_Whh, wbf);
  embed_kernel<<<8192, 256, 0, stream>>>(obsVel, mean, stdv, encW, encb, embed);

  dim3 grid(16, 32);
  int cur0 = 0, cur1 = 0;
  for (int t=0;t<8;t++){
    int ns = (t==0) ? 1 : 2;
    int cz = (t==0) ? 1 : 0;
    lstm_cell_kernel<<<grid, 256, 0, stream>>>(embed + t*512, 4096, h0[cur0], 512,
        w_lstm_ih, w_lstm_hh, lstm_b, c0, h0[cur0^1], 512, (ushort*)nullptr, 0, ns, cz);
    lstm_cell_kernel<<<grid, 256, 0, stream>>>(h0[cur0^1], 512, h1[cur1], 512,
        w_lstm_ih + 1048576, w_lstm_hh + 1048576, lstm_b + 2048, c1, h1[cur1^1], 512,
        (t==7) ? pred : (ushort*)nullptr, 6144, ns, cz);
    cur0 ^= 1; cur1 ^= 1;
  }
  for (int s=1;s<12;s++){
    lstm_cell_kernel<<<grid, 256, 0, stream>>>(pred + (s-1)*512, 6144, h0[cur0], 512,
        w_cell_ih, w_cell_hh, cell_b, c0, h0[cur0^1], 512, (ushort*)nullptr, 0, 2, 0);
    lstm_cell_kernel<<<grid, 256, 0, stream>>>(h0[cur0^1], 512, h1[cur1], 512,
        w_cell_ih + 1048576, w_cell_hh + 1048576, cell_b + 2048, c1, h1[cur1^1], 512,
        pred + s*512, 6144, 2, 0);
    cur0 ^= 1; cur1 ^= 1;
  }
  final_kernel<<<1024, 256, 0, stream>>>(pred, decW, decb, mean, stdv, obs, (float*)d_out);
}